// Round 1
// baseline (10666.748 us; speedup 1.0000x reference)
//
#include <hip/hip_runtime.h>
#include <math.h>

#define EPSBN 1e-3f

// ---------------- workspace layout (floats) ----------------
// 0     : w1f   480        (conv1 weights, BN1 folded)
// 480   : b1f   16
// 496   : b2f   32         (conv2 bias, BN2 folded)
// 528   : w2f   3072       (conv2 weights, BN2 folded)
// 3600  : Wt1   128*64     (LSTM1 [col][k], k = [x(32)|h(32)], BN3 folded into x-part)
// 11792 : Wt2   96*56      (LSTM2 [col][k], k = [h1(32)|h2(24)])
// 17168 : Wt3   64*40      (LSTM3 [col][k], k = [h2(24)|h3(16)])
// 19728 : bL1   128
// 19856 : bL2   96
// 19952 : bL3   64
// 20016 : r2    rows*505*32  (conv stack output, per chunk)
#define WS_W1F 0
#define WS_B1F 480
#define WS_B2F 496
#define WS_W2F 528
#define WS_WT1 3600
#define WS_WT2 11792
#define WS_WT3 17168
#define WS_BL1 19728
#define WS_BL2 19856
#define WS_BL3 19952
#define WS_R2  20016

// ---------------- prep: fold BN params, build layouts ----------------
__global__ __launch_bounds__(256) void prep_kernel(
    const float* __restrict__ bn1g, const float* __restrict__ bn1b,
    const float* __restrict__ bn1m, const float* __restrict__ bn1v,
    const float* __restrict__ bn2g, const float* __restrict__ bn2b,
    const float* __restrict__ bn2m, const float* __restrict__ bn2v,
    const float* __restrict__ bn3g, const float* __restrict__ bn3b,
    const float* __restrict__ bn3m, const float* __restrict__ bn3v,
    const float* __restrict__ c1w, const float* __restrict__ c1b,
    const float* __restrict__ c2w, const float* __restrict__ c2b,
    const float* __restrict__ l1W, const float* __restrict__ l1U, const float* __restrict__ l1b,
    const float* __restrict__ l2W, const float* __restrict__ l2U, const float* __restrict__ l2b,
    const float* __restrict__ l3W, const float* __restrict__ l3U, const float* __restrict__ l3b,
    float* __restrict__ ws)
{
  __shared__ float s1[10], t1[10], s2[16], t2[16], s3[32], t3[32];
  int tid = threadIdx.x;
  if (tid < 10)                  { float s = bn1g[tid] * rsqrtf(bn1v[tid] + EPSBN); s1[tid] = s; t1[tid] = bn1b[tid] - bn1m[tid] * s; }
  else if (tid >= 32 && tid < 48){ int c = tid - 32; float s = bn2g[c] * rsqrtf(bn2v[c] + EPSBN); s2[c] = s; t2[c] = bn2b[c] - bn2m[c] * s; }
  else if (tid >= 64 && tid < 96){ int c = tid - 64; float s = bn3g[c] * rsqrtf(bn3v[c] + EPSBN); s3[c] = s; t3[c] = bn3b[c] - bn3m[c] * s; }
  __syncthreads();

  float* w1f = ws + WS_W1F;
  float* b1f = ws + WS_B1F;
  float* b2f = ws + WS_B2F;
  float* w2f = ws + WS_W2F;
  float* Wt1 = ws + WS_WT1;
  float* Wt2 = ws + WS_WT2;
  float* Wt3 = ws + WS_WT3;
  float* bL1 = ws + WS_BL1;
  float* bL2 = ws + WS_BL2;
  float* bL3 = ws + WS_BL3;

  for (int i = tid; i < 480; i += 256) { int ci = (i >> 4) % 10; w1f[i] = c1w[i] * s1[ci]; }
  for (int co = tid; co < 16; co += 256) {
    float a = c1b[co];
    for (int k = 0; k < 3; k++) for (int ci = 0; ci < 10; ci++) a += t1[ci] * c1w[(k * 10 + ci) * 16 + co];
    b1f[co] = a;
  }
  for (int i = tid; i < 3072; i += 256) { int ci = (i >> 5) & 15; w2f[i] = c2w[i] * s2[ci]; }
  for (int co = tid; co < 32; co += 256) {
    float a = c2b[co];
    for (int k = 0; k < 6; k++) for (int ci = 0; ci < 16; ci++) a += t2[ci] * c2w[(k * 16 + ci) * 32 + co];
    b2f[co] = a;
  }
  // LSTM1: Wt1[j][kk] (j gate-col 0..127, kk 0..63), BN3 folded into x-rows
  for (int i = tid; i < 128 * 64; i += 256) {
    int j = i >> 6, kk = i & 63;
    Wt1[j * 64 + kk] = (kk < 32) ? l1W[kk * 128 + j] * s3[kk] : l1U[(kk - 32) * 128 + j];
  }
  for (int j = tid; j < 128; j += 256) {
    float a = l1b[j];
    for (int k = 0; k < 32; k++) a += t3[k] * l1W[k * 128 + j];
    bL1[j] = a;
  }
  for (int i = tid; i < 96 * 56; i += 256) {
    int j = i / 56, kk = i % 56;
    Wt2[i] = (kk < 32) ? l2W[kk * 96 + j] : l2U[(kk - 32) * 96 + j];
  }
  for (int j = tid; j < 96; j += 256) bL2[j] = l2b[j];
  for (int i = tid; i < 64 * 40; i += 256) {
    int j = i / 40, kk = i % 40;
    Wt3[i] = (kk < 24) ? l3W[kk * 64 + j] : l3U[(kk - 24) * 64 + j];
  }
  for (int j = tid; j < 64; j += 256) bL3[j] = l3b[j];
}

// ---------------- fused conv1+ReLU+conv2+ReLU (BN1/BN2 folded) ----------------
#define CT 128
__global__ __launch_bounds__(256) void conv_kernel(
    const float* __restrict__ x, const float* __restrict__ ws,
    float* __restrict__ r2, int row0)
{
  int b  = row0 + blockIdx.y;        // global batch row
  int bl = blockIdx.y;               // local row within chunk
  int t0 = blockIdx.x * CT;
  int n2 = min(CT, 505 - t0);        // r2 outputs in tile
  int n1 = n2 + 5;                   // r1 entries needed
  int nx = n1 + 2;                   // x entries needed
  int tid = threadIdx.x;

  __shared__ float xs[135 * 10];
  __shared__ float r1s[133 * 17];            // stride 17 to kill 32-way bank conflicts
  __shared__ float w1f[480];
  __shared__ float b1f[16];
  alignas(16) __shared__ float w2f[3072];
  __shared__ float b2f[32];

  for (int i = tid; i < 480;  i += 256) w1f[i] = ws[WS_W1F + i];
  for (int i = tid; i < 16;   i += 256) b1f[i] = ws[WS_B1F + i];
  for (int i = tid; i < 32;   i += 256) b2f[i] = ws[WS_B2F + i];
  for (int i = tid; i < 3072; i += 256) w2f[i] = ws[WS_W2F + i];
  const float* xb = x + (size_t)b * 512 * 10 + (size_t)t0 * 10;
  for (int i = tid; i < nx * 10; i += 256) xs[i] = xb[i];
  __syncthreads();

  // conv1 + relu
  for (int i = tid; i < n1 * 16; i += 256) {
    int tt = i >> 4, c = i & 15;
    float a = b1f[c];
    #pragma unroll
    for (int k = 0; k < 3; k++)
      #pragma unroll
      for (int ci = 0; ci < 10; ci++)
        a = fmaf(xs[(tt + k) * 10 + ci], w1f[(k * 10 + ci) * 16 + c], a);
    r1s[tt * 17 + c] = fmaxf(a, 0.f);
  }
  __syncthreads();

  // conv2 + relu, register-blocked 4co x 4t
  int cog = (tid & 7) * 4;
  int tg  = (tid >> 3) * 4;
  float acc[4][4];
  #pragma unroll
  for (int i2 = 0; i2 < 4; i2++)
    #pragma unroll
    for (int j2 = 0; j2 < 4; j2++) acc[i2][j2] = b2f[cog + j2];
  #pragma unroll
  for (int k2 = 0; k2 < 6; k2++)
    #pragma unroll
    for (int ci = 0; ci < 16; ci++) {
      float4 w4 = *(const float4*)&w2f[(k2 * 16 + ci) * 32 + cog];
      #pragma unroll
      for (int i2 = 0; i2 < 4; i2++) {
        float xv = r1s[(tg + i2 + k2) * 17 + ci];
        acc[i2][0] = fmaf(xv, w4.x, acc[i2][0]);
        acc[i2][1] = fmaf(xv, w4.y, acc[i2][1]);
        acc[i2][2] = fmaf(xv, w4.z, acc[i2][2]);
        acc[i2][3] = fmaf(xv, w4.w, acc[i2][3]);
      }
    }
  #pragma unroll
  for (int i2 = 0; i2 < 4; i2++) {
    int tt = tg + i2;
    if (tt < n2) {
      float4 o;
      o.x = fmaxf(acc[i2][0], 0.f); o.y = fmaxf(acc[i2][1], 0.f);
      o.z = fmaxf(acc[i2][2], 0.f); o.w = fmaxf(acc[i2][3], 0.f);
      *(float4*)&r2[((size_t)bl * 505 + (t0 + tt)) * 32 + cog] = o;
    }
  }
}

// ---------------- LSTM chain (3 layers stepped together) + dense head ----------------
__device__ __forceinline__ float sigm(float v) { return 1.f / (1.f + __expf(-v)); }
__device__ __forceinline__ float tanh_(float v) {
  float e = __expf(-2.f * fabsf(v));
  float t = (1.f - e) / (1.f + e);
  return copysignf(t, v);
}

template<int D, int NCOL>
__device__ __forceinline__ void zphase(const float* __restrict__ xh, float* __restrict__ zbuf,
                                       const float (&w)[D], float bias, int lane, int a, int bb)
{
  int j = a * 64 + lane;
  float s0 = xh[(bb * 4 + 0) * 64 + lane];
  float s1 = xh[(bb * 4 + 1) * 64 + lane];
  float s2 = xh[(bb * 4 + 2) * 64 + lane];
  float s3 = xh[(bb * 4 + 3) * 64 + lane];
  float z0 = bias, z1 = bias, z2 = bias, z3 = bias;
  #pragma unroll
  for (int k = 0; k < D; k++) {
    float a0 = __int_as_float(__builtin_amdgcn_readlane(__float_as_int(s0), k));
    float a1 = __int_as_float(__builtin_amdgcn_readlane(__float_as_int(s1), k));
    float a2 = __int_as_float(__builtin_amdgcn_readlane(__float_as_int(s2), k));
    float a3 = __int_as_float(__builtin_amdgcn_readlane(__float_as_int(s3), k));
    z0 = fmaf(w[k], a0, z0);
    z1 = fmaf(w[k], a1, z1);
    z2 = fmaf(w[k], a2, z2);
    z3 = fmaf(w[k], a3, z3);
  }
  if (j < NCOL) {
    zbuf[(bb * 4 + 0) * 128 + j] = z0;
    zbuf[(bb * 4 + 1) * 128 + j] = z1;
    zbuf[(bb * 4 + 2) * 128 + j] = z2;
    zbuf[(bb * 4 + 3) * 128 + j] = z3;
  }
}

template<int IN, int H>
__device__ __forceinline__ void update_phase(const float* __restrict__ zbuf, float* __restrict__ cbuf,
                                             float* __restrict__ xh_cur, float* __restrict__ xh_next,
                                             int tid)
{
  int u = tid % H;
  int row = tid / H;
  if (row < 8) {
    float zi = zbuf[row * 128 + u];
    float zf = zbuf[row * 128 + H + u];
    float zg = zbuf[row * 128 + 2 * H + u];
    float zo = zbuf[row * 128 + 3 * H + u];
    float gi = sigm(zi), gf = sigm(zf), gg = tanh_(zg), go = sigm(zo);
    float c = cbuf[row * H + u];
    c = fmaf(gf, c, gi * gg);
    cbuf[row * H + u] = c;
    float h = go * tanh_(c);
    xh_cur[row * 64 + IN + u] = h;
    if (xh_next) xh_next[row * 64 + u] = h;
  }
}

__global__ __launch_bounds__(256, 2) void lstm_kernel(
    const float* __restrict__ r2, const float* __restrict__ ws,
    const float* __restrict__ d1w, const float* __restrict__ d1b,
    const float* __restrict__ outw, const float* __restrict__ outb,
    float* __restrict__ out, int row0)
{
  const float* Wt1 = ws + WS_WT1;
  const float* Wt2 = ws + WS_WT2;
  const float* Wt3 = ws + WS_WT3;

  int tid  = threadIdx.x;
  int lane = tid & 63;
  int wv   = tid >> 6;
  int a    = wv & 1;    // unit-half
  int bb   = wv >> 1;   // row-half
  int rl   = blockIdx.x * 8;        // local row base within chunk

  __shared__ float xh1[8 * 64];
  __shared__ float xh2[8 * 64];
  __shared__ float xh3[8 * 64];
  __shared__ float zb [8 * 128];
  __shared__ float c1 [8 * 32];
  __shared__ float c2 [8 * 24];
  __shared__ float c3 [8 * 16];

  for (int i = tid; i < 8 * 64; i += 256) { xh1[i] = 0.f; xh2[i] = 0.f; xh3[i] = 0.f; }
  for (int i = tid; i < 8 * 32; i += 256) c1[i] = 0.f;
  for (int i = tid; i < 8 * 24; i += 256) c2[i] = 0.f;
  for (int i = tid; i < 8 * 16; i += 256) c3[i] = 0.f;

  // weight columns -> registers (reused 505x)
  int j1 = a * 64 + lane;
  int j2 = a * 64 + lane;
  float w1[64], w2[56], w3[40];
  #pragma unroll
  for (int q = 0; q < 16; q++) {
    float4 v = *(const float4*)&Wt1[j1 * 64 + q * 4];
    w1[q*4] = v.x; w1[q*4+1] = v.y; w1[q*4+2] = v.z; w1[q*4+3] = v.w;
  }
  if (j2 < 96) {
    #pragma unroll
    for (int q = 0; q < 14; q++) {
      float4 v = *(const float4*)&Wt2[j2 * 56 + q * 4];
      w2[q*4] = v.x; w2[q*4+1] = v.y; w2[q*4+2] = v.z; w2[q*4+3] = v.w;
    }
  } else {
    #pragma unroll
    for (int q = 0; q < 56; q++) w2[q] = 0.f;
  }
  if (a == 0) {
    #pragma unroll
    for (int q = 0; q < 10; q++) {
      float4 v = *(const float4*)&Wt3[lane * 40 + q * 4];
      w3[q*4] = v.x; w3[q*4+1] = v.y; w3[q*4+2] = v.z; w3[q*4+3] = v.w;
    }
  } else {
    #pragma unroll
    for (int q = 0; q < 40; q++) w3[q] = 0.f;
  }
  float bias1 = ws[WS_BL1 + j1];
  float bias2 = (j2 < 96) ? ws[WS_BL2 + j2] : 0.f;
  float bias3 = (a == 0) ? ws[WS_BL3 + lane] : 0.f;

  __syncthreads();

  for (int t = 0; t < 505; ++t) {
    { // stream in x_t = conv output (32 ch) for the 8 rows
      int rr = tid >> 5, kk = tid & 31;
      xh1[rr * 64 + kk] = r2[((size_t)(rl + rr) * 505 + t) * 32 + kk];
    }
    __syncthreads();
    zphase<64, 128>(xh1, zb, w1, bias1, lane, a, bb);
    __syncthreads();
    update_phase<32, 32>(zb, c1, xh1, xh2, tid);
    __syncthreads();
    zphase<56, 96>(xh2, zb, w2, bias2, lane, a, bb);
    __syncthreads();
    update_phase<32, 24>(zb, c2, xh2, xh3, tid);
    __syncthreads();
    if (a == 0) zphase<40, 64>(xh3, zb, w3, bias3, lane, 0, bb);
    __syncthreads();
    update_phase<24, 16>(zb, c3, xh3, nullptr, tid);
    __syncthreads();
  }

  // dense(16->8)+relu, dense(8->5)+softmax; h3 sits at xh3[row][24..39]
  if (tid < 8) {
    int row = tid;
    float hd[16];
    #pragma unroll
    for (int u = 0; u < 16; u++) hd[u] = xh3[row * 64 + 24 + u];
    float aa[8];
    #pragma unroll
    for (int o = 0; o < 8; o++) {
      float acc = d1b[o];
      #pragma unroll
      for (int u = 0; u < 16; u++) acc = fmaf(hd[u], d1w[u * 8 + o], acc);
      aa[o] = fmaxf(acc, 0.f);
    }
    float oo[5]; float mx = -1e30f;
    #pragma unroll
    for (int cc = 0; cc < 5; cc++) {
      float acc = outb[cc];
      #pragma unroll
      for (int o = 0; o < 8; o++) acc = fmaf(aa[o], outw[o * 5 + cc], acc);
      oo[cc] = acc; mx = fmaxf(mx, acc);
    }
    float sum = 0.f;
    #pragma unroll
    for (int cc = 0; cc < 5; cc++) { oo[cc] = __expf(oo[cc] - mx); sum += oo[cc]; }
    float inv = 1.f / sum;
    #pragma unroll
    for (int cc = 0; cc < 5; cc++) out[(size_t)(row0 + rl + row) * 5 + cc] = oo[cc] * inv;
  }
}

// ---------------- launch ----------------
extern "C" void kernel_launch(void* const* d_in, const int* in_sizes, int n_in,
                              void* d_out, int out_size, void* d_ws, size_t ws_size,
                              hipStream_t stream)
{
  const float* x    = (const float*)d_in[0];
  const float* bn1g = (const float*)d_in[1];
  const float* bn1b = (const float*)d_in[2];
  const float* bn1m = (const float*)d_in[3];
  const float* bn1v = (const float*)d_in[4];
  const float* bn2g = (const float*)d_in[5];
  const float* bn2b = (const float*)d_in[6];
  const float* bn2m = (const float*)d_in[7];
  const float* bn2v = (const float*)d_in[8];
  const float* bn3g = (const float*)d_in[9];
  const float* bn3b = (const float*)d_in[10];
  const float* bn3v_ = (const float*)d_in[12];
  const float* bn3m = (const float*)d_in[11];
  const float* c1w  = (const float*)d_in[13];
  const float* c1b  = (const float*)d_in[14];
  const float* c2w  = (const float*)d_in[15];
  const float* c2b  = (const float*)d_in[16];
  const float* l1W  = (const float*)d_in[17];
  const float* l1U  = (const float*)d_in[18];
  const float* l1b  = (const float*)d_in[19];
  const float* l2W  = (const float*)d_in[20];
  const float* l2U  = (const float*)d_in[21];
  const float* l2b  = (const float*)d_in[22];
  const float* l3W  = (const float*)d_in[23];
  const float* l3U  = (const float*)d_in[24];
  const float* l3b  = (const float*)d_in[25];
  const float* d1w  = (const float*)d_in[26];
  const float* d1b  = (const float*)d_in[27];
  const float* outw = (const float*)d_in[28];
  const float* outb = (const float*)d_in[29];

  float* ws = (float*)d_ws;
  float* r2 = ws + WS_R2;

  prep_kernel<<<1, 256, 0, stream>>>(bn1g, bn1b, bn1m, bn1v,
                                     bn2g, bn2b, bn2m, bn2v,
                                     bn3g, bn3b, bn3m, bn3v_,
                                     c1w, c1b, c2w, c2b,
                                     l1W, l1U, l1b, l2W, l2U, l2b, l3W, l3U, l3b,
                                     ws);

  // chunk batch if workspace is too small for the full r2 buffer (265 MB)
  size_t avail = (ws_size / 4 > (size_t)WS_R2) ? ws_size / 4 - WS_R2 : 0;
  int nch = 1;
  while ((size_t)(4096 / nch) * 505 * 32 > avail && nch < 8) nch <<= 1;
  int rows_pc = 4096 / nch;

  for (int ch = 0; ch < nch; ++ch) {
    int row0 = ch * rows_pc;
    dim3 cgrid(4, rows_pc);
    conv_kernel<<<cgrid, 256, 0, stream>>>(x, ws, r2, row0);
    lstm_kernel<<<rows_pc / 8, 256, 0, stream>>>(r2, ws, d1w, d1b, outw, outb, (float*)d_out, row0);
  }
}

// Round 2
// 4602.774 us; speedup vs baseline: 2.3175x; 2.3175x over previous
//
#include <hip/hip_runtime.h>
#include <math.h>

#define EPSBN 1e-3f

// ---------------- workspace layout (floats) ----------------
#define WS_W1F 0
#define WS_B1F 480
#define WS_B2F 496
#define WS_W2F 528
#define WS_WT1 3600
#define WS_WT2 11792
#define WS_WT3 17168
#define WS_BL1 19728
#define WS_BL2 19856
#define WS_BL3 19952
#define WS_R2  20016

// ---------------- prep: fold BN params, build layouts ----------------
__global__ __launch_bounds__(256) void prep_kernel(
    const float* __restrict__ bn1g, const float* __restrict__ bn1b,
    const float* __restrict__ bn1m, const float* __restrict__ bn1v,
    const float* __restrict__ bn2g, const float* __restrict__ bn2b,
    const float* __restrict__ bn2m, const float* __restrict__ bn2v,
    const float* __restrict__ bn3g, const float* __restrict__ bn3b,
    const float* __restrict__ bn3m, const float* __restrict__ bn3v,
    const float* __restrict__ c1w, const float* __restrict__ c1b,
    const float* __restrict__ c2w, const float* __restrict__ c2b,
    const float* __restrict__ l1W, const float* __restrict__ l1U, const float* __restrict__ l1b,
    const float* __restrict__ l2W, const float* __restrict__ l2U, const float* __restrict__ l2b,
    const float* __restrict__ l3W, const float* __restrict__ l3U, const float* __restrict__ l3b,
    float* __restrict__ ws)
{
  __shared__ float s1[10], t1[10], s2[16], t2[16], s3[32], t3[32];
  int tid = threadIdx.x;
  if (tid < 10)                  { float s = bn1g[tid] * rsqrtf(bn1v[tid] + EPSBN); s1[tid] = s; t1[tid] = bn1b[tid] - bn1m[tid] * s; }
  else if (tid >= 32 && tid < 48){ int c = tid - 32; float s = bn2g[c] * rsqrtf(bn2v[c] + EPSBN); s2[c] = s; t2[c] = bn2b[c] - bn2m[c] * s; }
  else if (tid >= 64 && tid < 96){ int c = tid - 64; float s = bn3g[c] * rsqrtf(bn3v[c] + EPSBN); s3[c] = s; t3[c] = bn3b[c] - bn3m[c] * s; }
  __syncthreads();

  float* w1f = ws + WS_W1F;
  float* b1f = ws + WS_B1F;
  float* b2f = ws + WS_B2F;
  float* w2f = ws + WS_W2F;
  float* Wt1 = ws + WS_WT1;
  float* Wt2 = ws + WS_WT2;
  float* Wt3 = ws + WS_WT3;
  float* bL1 = ws + WS_BL1;
  float* bL2 = ws + WS_BL2;
  float* bL3 = ws + WS_BL3;

  for (int i = tid; i < 480; i += 256) { int ci = (i >> 4) % 10; w1f[i] = c1w[i] * s1[ci]; }
  for (int co = tid; co < 16; co += 256) {
    float a = c1b[co];
    for (int k = 0; k < 3; k++) for (int ci = 0; ci < 10; ci++) a += t1[ci] * c1w[(k * 10 + ci) * 16 + co];
    b1f[co] = a;
  }
  for (int i = tid; i < 3072; i += 256) { int ci = (i >> 5) & 15; w2f[i] = c2w[i] * s2[ci]; }
  for (int co = tid; co < 32; co += 256) {
    float a = c2b[co];
    for (int k = 0; k < 6; k++) for (int ci = 0; ci < 16; ci++) a += t2[ci] * c2w[(k * 16 + ci) * 32 + co];
    b2f[co] = a;
  }
  for (int i = tid; i < 128 * 64; i += 256) {
    int j = i >> 6, kk = i & 63;
    Wt1[j * 64 + kk] = (kk < 32) ? l1W[kk * 128 + j] * s3[kk] : l1U[(kk - 32) * 128 + j];
  }
  for (int j = tid; j < 128; j += 256) {
    float a = l1b[j];
    for (int k = 0; k < 32; k++) a += t3[k] * l1W[k * 128 + j];
    bL1[j] = a;
  }
  for (int i = tid; i < 96 * 56; i += 256) {
    int j = i / 56, kk = i % 56;
    Wt2[i] = (kk < 32) ? l2W[kk * 96 + j] : l2U[(kk - 32) * 96 + j];
  }
  for (int j = tid; j < 96; j += 256) bL2[j] = l2b[j];
  for (int i = tid; i < 64 * 40; i += 256) {
    int j = i / 40, kk = i % 40;
    Wt3[i] = (kk < 24) ? l3W[kk * 64 + j] : l3U[(kk - 24) * 64 + j];
  }
  for (int j = tid; j < 64; j += 256) bL3[j] = l3b[j];
}

// ---------------- fused conv1+ReLU+conv2+ReLU (BN1/BN2 folded) ----------------
// __launch_bounds__(256,4): cap VGPRs at 128 (round-1 version spilled at 256 VGPR,
// 16.9 GB of scratch traffic). #pragma unroll 4 keeps the live LDS-load window small.
#define CT 128
__global__ __launch_bounds__(256, 4) void conv_kernel(
    const float* __restrict__ x, const float* __restrict__ ws,
    float* __restrict__ r2, int row0)
{
  int b  = row0 + blockIdx.y;
  int bl = blockIdx.y;
  int t0 = blockIdx.x * CT;
  int n2 = min(CT, 505 - t0);
  int n1 = n2 + 5;
  int nx = n1 + 2;
  int tid = threadIdx.x;

  __shared__ float xs[135 * 10];
  __shared__ float r1s[133 * 17];
  __shared__ float w1f[480];
  __shared__ float b1f[16];
  alignas(16) __shared__ float w2f[3072];
  __shared__ float b2f[32];

  for (int i = tid; i < 480;  i += 256) w1f[i] = ws[WS_W1F + i];
  for (int i = tid; i < 16;   i += 256) b1f[i] = ws[WS_B1F + i];
  for (int i = tid; i < 32;   i += 256) b2f[i] = ws[WS_B2F + i];
  for (int i = tid; i < 3072; i += 256) w2f[i] = ws[WS_W2F + i];
  const float* xb = x + (size_t)b * 512 * 10 + (size_t)t0 * 10;
  for (int i = tid; i < nx * 10; i += 256) xs[i] = xb[i];
  __syncthreads();

  // conv1 + relu
  #pragma unroll 1
  for (int i = tid; i < n1 * 16; i += 256) {
    int tt = i >> 4, c = i & 15;
    float a = b1f[c];
    #pragma unroll
    for (int k = 0; k < 3; k++)
      #pragma unroll
      for (int ci = 0; ci < 10; ci++)
        a = fmaf(xs[(tt + k) * 10 + ci], w1f[(k * 10 + ci) * 16 + c], a);
    r1s[tt * 17 + c] = fmaxf(a, 0.f);
  }
  __syncthreads();

  // conv2 + relu, register-blocked 4co x 4t, bounded unroll
  int cog = (tid & 7) * 4;
  int tg  = (tid >> 3) * 4;
  float acc[4][4];
  #pragma unroll
  for (int i2 = 0; i2 < 4; i2++)
    #pragma unroll
    for (int j2 = 0; j2 < 4; j2++) acc[i2][j2] = b2f[cog + j2];
  #pragma unroll 4
  for (int kc = 0; kc < 96; kc++) {
    int k2 = kc >> 4;
    float4 w4 = *(const float4*)&w2f[kc * 32 + cog];
    #pragma unroll
    for (int i2 = 0; i2 < 4; i2++) {
      float xv = r1s[(tg + i2 + k2) * 17 + (kc & 15)];
      acc[i2][0] = fmaf(xv, w4.x, acc[i2][0]);
      acc[i2][1] = fmaf(xv, w4.y, acc[i2][1]);
      acc[i2][2] = fmaf(xv, w4.z, acc[i2][2]);
      acc[i2][3] = fmaf(xv, w4.w, acc[i2][3]);
    }
  }
  #pragma unroll
  for (int i2 = 0; i2 < 4; i2++) {
    int tt = tg + i2;
    if (tt < n2) {
      float4 o;
      o.x = fmaxf(acc[i2][0], 0.f); o.y = fmaxf(acc[i2][1], 0.f);
      o.z = fmaxf(acc[i2][2], 0.f); o.w = fmaxf(acc[i2][3], 0.f);
      *(float4*)&r2[((size_t)bl * 505 + (t0 + tt)) * 32 + cog] = o;
    }
  }
}

// ---------------- LSTM chain (3 layers stepped together) + dense head ----------------
__device__ __forceinline__ float sigm(float v) { return 1.f / (1.f + __expf(-v)); }
__device__ __forceinline__ float tanh_(float v) {
  float e = __expf(-2.f * fabsf(v));
  float t = (1.f - e) / (1.f + e);
  return copysignf(t, v);
}

// lane j (= colbase+lane) computes z[cols j] for rows rowbase..rowbase+NR-1
template<int D, int NCOL, int NR>
__device__ __forceinline__ void zphase(const float* __restrict__ xh, float* __restrict__ zbuf,
                                       const float (&w)[D], float bias,
                                       int lane, int colbase, int rowbase)
{
  int j = colbase + lane;
  float s[NR], z[NR];
  #pragma unroll
  for (int r = 0; r < NR; r++) { s[r] = xh[(rowbase + r) * 64 + lane]; z[r] = bias; }
  #pragma unroll
  for (int k = 0; k < D; k++) {
    #pragma unroll
    for (int r = 0; r < NR; r++) {
      float hv = __int_as_float(__builtin_amdgcn_readlane(__float_as_int(s[r]), k));
      z[r] = fmaf(w[k], hv, z[r]);
    }
  }
  if (j < NCOL) {
    #pragma unroll
    for (int r = 0; r < NR; r++) zbuf[(rowbase + r) * 128 + j] = z[r];
  }
}

// gate update; cell state lives in a per-thread register (thread<->unit map is step-invariant)
template<int IN, int H>
__device__ __forceinline__ void update_phase(const float* __restrict__ zbuf, float& creg,
                                             float* __restrict__ xh_cur, float* __restrict__ xh_next,
                                             int u, int row)
{
  if (row < 4) {
    float zi = zbuf[row * 128 + u];
    float zf = zbuf[row * 128 + H + u];
    float zg = zbuf[row * 128 + 2 * H + u];
    float zo = zbuf[row * 128 + 3 * H + u];
    float gi = sigm(zi), gf = sigm(zf), gg = tanh_(zg), go = sigm(zo);
    creg = fmaf(gf, creg, gi * gg);
    float h = go * tanh_(creg);
    xh_cur[row * 64 + IN + u] = h;
    if (xh_next) xh_next[row * 64 + u] = h;
  }
}

// 4 batch-rows per block, 128 threads (2 waves). 6 barriers/step, x prefetched.
__global__ __launch_bounds__(128, 2) void lstm_kernel(
    const float* __restrict__ r2, const float* __restrict__ ws,
    const float* __restrict__ d1w, const float* __restrict__ d1b,
    const float* __restrict__ outw, const float* __restrict__ outb,
    float* __restrict__ out, int row0)
{
  const float* Wt1 = ws + WS_WT1;
  const float* Wt2 = ws + WS_WT2;
  const float* Wt3 = ws + WS_WT3;

  int tid  = threadIdx.x;
  int lane = tid & 63;
  int a    = tid >> 6;          // wave id (0/1)
  int rl   = blockIdx.x * 4;    // local row base within chunk

  __shared__ float xh1[4 * 64];
  __shared__ float xh2[4 * 64];
  __shared__ float xh3[4 * 64];
  __shared__ float zb [4 * 128];

  for (int i = tid; i < 4 * 64; i += 128) { xh1[i] = 0.f; xh2[i] = 0.f; xh3[i] = 0.f; }

  // per-thread cell-state registers
  int u1i = tid & 31,  r1i = tid >> 5;                 // L1: all 128 threads
  int u2i = tid % 24,  r2i = tid / 24;                 // L2: threads with r2i<4
  int u3i = tid & 15,  r3i = tid >> 4;                 // L3: threads with r3i<4
  float c1r = 0.f, c2r = 0.f, c3r = 0.f;

  // weight columns -> registers (reused 505x)
  int j1 = a * 64 + lane;
  float w1[64], w2[56], w3[40];
  #pragma unroll
  for (int q = 0; q < 16; q++) {
    float4 v = *(const float4*)&Wt1[j1 * 64 + q * 4];
    w1[q*4] = v.x; w1[q*4+1] = v.y; w1[q*4+2] = v.z; w1[q*4+3] = v.w;
  }
  if (j1 < 96) {
    #pragma unroll
    for (int q = 0; q < 14; q++) {
      float4 v = *(const float4*)&Wt2[j1 * 56 + q * 4];
      w2[q*4] = v.x; w2[q*4+1] = v.y; w2[q*4+2] = v.z; w2[q*4+3] = v.w;
    }
  } else {
    #pragma unroll
    for (int q = 0; q < 56; q++) w2[q] = 0.f;
  }
  #pragma unroll
  for (int q = 0; q < 10; q++) {
    float4 v = *(const float4*)&Wt3[lane * 40 + q * 4];
    w3[q*4] = v.x; w3[q*4+1] = v.y; w3[q*4+2] = v.z; w3[q*4+3] = v.w;
  }
  float bias1 = ws[WS_BL1 + j1];
  float bias2 = (j1 < 96) ? ws[WS_BL2 + j1] : 0.f;
  float bias3 = ws[WS_BL3 + lane];

  // x_0 into LDS; x_1 into prefetch register
  int rr = tid >> 5, kk = tid & 31;
  const float* r2row = r2 + ((size_t)(rl + rr) * 505) * 32 + kk;
  xh1[rr * 64 + kk] = r2row[0];
  float xnext = r2row[32];
  __syncthreads();

  for (int t = 0; t < 505; ++t) {
    zphase<64, 128, 4>(xh1, zb, w1, bias1, lane, a * 64, 0);
    __syncthreads();                                   // B1
    if (t < 504) xh1[rr * 64 + kk] = xnext;            // stage x_{t+1} (z1 already consumed x_t)
    update_phase<32, 32>(zb, c1r, xh1, xh2, u1i, r1i);
    if (t < 503) xnext = r2row[(size_t)(t + 2) * 32];  // prefetch x_{t+2}, hides under z2/z3
    __syncthreads();                                   // B2
    zphase<56, 96, 4>(xh2, zb, w2, bias2, lane, a * 64, 0);
    __syncthreads();                                   // B3
    update_phase<32, 24>(zb, c2r, xh2, xh3, u2i, r2i);
    __syncthreads();                                   // B4
    zphase<40, 64, 2>(xh3, zb, w3, bias3, lane, 0, a * 2);  // both waves: 2 rows each
    __syncthreads();                                   // B5
    update_phase<24, 16>(zb, c3r, xh3, nullptr, u3i, r3i);
    __syncthreads();                                   // B6
  }

  // dense(16->8)+relu, dense(8->5)+softmax; h3 at xh3[row][24..39]
  if (tid < 4) {
    int row = tid;
    float hd[16];
    #pragma unroll
    for (int u = 0; u < 16; u++) hd[u] = xh3[row * 64 + 24 + u];
    float aa[8];
    #pragma unroll
    for (int o = 0; o < 8; o++) {
      float acc = d1b[o];
      #pragma unroll
      for (int u = 0; u < 16; u++) acc = fmaf(hd[u], d1w[u * 8 + o], acc);
      aa[o] = fmaxf(acc, 0.f);
    }
    float oo[5]; float mx = -1e30f;
    #pragma unroll
    for (int cc = 0; cc < 5; cc++) {
      float acc = outb[cc];
      #pragma unroll
      for (int o = 0; o < 8; o++) acc = fmaf(aa[o], outw[o * 5 + cc], acc);
      oo[cc] = acc; mx = fmaxf(mx, acc);
    }
    float sum = 0.f;
    #pragma unroll
    for (int cc = 0; cc < 5; cc++) { oo[cc] = __expf(oo[cc] - mx); sum += oo[cc]; }
    float inv = 1.f / sum;
    #pragma unroll
    for (int cc = 0; cc < 5; cc++) out[(size_t)(row0 + rl + row) * 5 + cc] = oo[cc] * inv;
  }
}

// ---------------- launch ----------------
extern "C" void kernel_launch(void* const* d_in, const int* in_sizes, int n_in,
                              void* d_out, int out_size, void* d_ws, size_t ws_size,
                              hipStream_t stream)
{
  const float* x    = (const float*)d_in[0];
  const float* bn1g = (const float*)d_in[1];
  const float* bn1b = (const float*)d_in[2];
  const float* bn1m = (const float*)d_in[3];
  const float* bn1v = (const float*)d_in[4];
  const float* bn2g = (const float*)d_in[5];
  const float* bn2b = (const float*)d_in[6];
  const float* bn2m = (const float*)d_in[7];
  const float* bn2v = (const float*)d_in[8];
  const float* bn3g = (const float*)d_in[9];
  const float* bn3b = (const float*)d_in[10];
  const float* bn3m = (const float*)d_in[11];
  const float* bn3v = (const float*)d_in[12];
  const float* c1w  = (const float*)d_in[13];
  const float* c1b  = (const float*)d_in[14];
  const float* c2w  = (const float*)d_in[15];
  const float* c2b  = (const float*)d_in[16];
  const float* l1W  = (const float*)d_in[17];
  const float* l1U  = (const float*)d_in[18];
  const float* l1b  = (const float*)d_in[19];
  const float* l2W  = (const float*)d_in[20];
  const float* l2U  = (const float*)d_in[21];
  const float* l2b  = (const float*)d_in[22];
  const float* l3W  = (const float*)d_in[23];
  const float* l3U  = (const float*)d_in[24];
  const float* l3b  = (const float*)d_in[25];
  const float* d1w  = (const float*)d_in[26];
  const float* d1b  = (const float*)d_in[27];
  const float* outw = (const float*)d_in[28];
  const float* outb = (const float*)d_in[29];

  float* ws = (float*)d_ws;
  float* r2 = ws + WS_R2;

  prep_kernel<<<1, 256, 0, stream>>>(bn1g, bn1b, bn1m, bn1v,
                                     bn2g, bn2b, bn2m, bn2v,
                                     bn3g, bn3b, bn3m, bn3v,
                                     c1w, c1b, c2w, c2b,
                                     l1W, l1U, l1b, l2W, l2U, l2b, l3W, l3U, l3b,
                                     ws);

  size_t avail = (ws_size / 4 > (size_t)WS_R2) ? ws_size / 4 - WS_R2 : 0;
  int nch = 1;
  while ((size_t)(4096 / nch) * 505 * 32 > avail && nch < 8) nch <<= 1;
  int rows_pc = 4096 / nch;

  for (int ch = 0; ch < nch; ++ch) {
    int row0 = ch * rows_pc;
    dim3 cgrid(4, rows_pc);
    conv_kernel<<<cgrid, 256, 0, stream>>>(x, ws, r2, row0);
    lstm_kernel<<<rows_pc / 4, 128, 0, stream>>>(r2, ws, d1w, d1b, outw, outb, (float*)d_out, row0);
  }
}

// Round 3
// 1310.896 us; speedup vs baseline: 8.1370x; 3.5112x over previous
//
#include <hip/hip_runtime.h>
#include <math.h>

#define EPSBN 1e-3f

typedef unsigned long long ull;
typedef __attribute__((ext_vector_type(8))) short bf16x8;
typedef __attribute__((ext_vector_type(4))) float f32x4;

// ---------------- workspace layout (float offsets) ----------------
#define WS_W1F 0        // 480   conv1 w (BN1 folded)
#define WS_B1F 480      // 16
#define WS_B2F 496      // 32
#define WS_W2F 528      // 3072  conv2 w (BN2 folded) -> 3600
#define WS_BL1 3600     // 128   lstm1 bias (BN3 folded)
#define WS_BL2 3728     // 96
#define WS_BL3 3824     // 64 -> 3888
#define WS_B1P 3888     // 8192 ushort (bf16 B-frags L1) = 4096 f -> 7984
#define WS_B2P 7984     // 6144 ushort = 3072 f -> 11056
#define WS_B3P 11056    // 4096 ushort = 2048 f -> 13104
#define WS_R2  13104    // r2 in bf16 (ushort), rows*505*32

__device__ __forceinline__ unsigned short f2b(float f) {
  unsigned u = __float_as_uint(f);
  return (unsigned short)((u + 0x7FFFu + ((u >> 16) & 1u)) >> 16);  // RNE
}
__device__ __forceinline__ float sigm(float v) { return 1.f / (1.f + __expf(-v)); }
__device__ __forceinline__ float tanh_(float v) {
  float e = __expf(-2.f * fabsf(v));
  float t = (1.f - e) / (1.f + e);
  return copysignf(t, v);
}

// ---------------- prep: fold BN, pack MFMA B-fragments (bf16) ----------------
__global__ __launch_bounds__(256) void prep_kernel(
    const float* __restrict__ bn1g, const float* __restrict__ bn1b,
    const float* __restrict__ bn1m, const float* __restrict__ bn1v,
    const float* __restrict__ bn2g, const float* __restrict__ bn2b,
    const float* __restrict__ bn2m, const float* __restrict__ bn2v,
    const float* __restrict__ bn3g, const float* __restrict__ bn3b,
    const float* __restrict__ bn3m, const float* __restrict__ bn3v,
    const float* __restrict__ c1w, const float* __restrict__ c1b,
    const float* __restrict__ c2w, const float* __restrict__ c2b,
    const float* __restrict__ l1W, const float* __restrict__ l1U, const float* __restrict__ l1b,
    const float* __restrict__ l2W, const float* __restrict__ l2U, const float* __restrict__ l2b,
    const float* __restrict__ l3W, const float* __restrict__ l3U, const float* __restrict__ l3b,
    float* __restrict__ ws)
{
  __shared__ float s1[10], t1[10], s2[16], t2[16], s3[32], t3[32];
  int tid = threadIdx.x;
  if (tid < 10)                  { float s = bn1g[tid] * rsqrtf(bn1v[tid] + EPSBN); s1[tid] = s; t1[tid] = bn1b[tid] - bn1m[tid] * s; }
  else if (tid >= 32 && tid < 48){ int c = tid - 32; float s = bn2g[c] * rsqrtf(bn2v[c] + EPSBN); s2[c] = s; t2[c] = bn2b[c] - bn2m[c] * s; }
  else if (tid >= 64 && tid < 96){ int c = tid - 64; float s = bn3g[c] * rsqrtf(bn3v[c] + EPSBN); s3[c] = s; t3[c] = bn3b[c] - bn3m[c] * s; }
  __syncthreads();

  float* w1f = ws + WS_W1F;
  float* b1f = ws + WS_B1F;
  float* b2f = ws + WS_B2F;
  float* w2f = ws + WS_W2F;
  float* bL1 = ws + WS_BL1;
  float* bL2 = ws + WS_BL2;
  float* bL3 = ws + WS_BL3;
  unsigned short* B1P = (unsigned short*)(ws + WS_B1P);
  unsigned short* B2P = (unsigned short*)(ws + WS_B2P);
  unsigned short* B3P = (unsigned short*)(ws + WS_B3P);

  for (int i = tid; i < 480; i += 256) { int ci = (i >> 4) % 10; w1f[i] = c1w[i] * s1[ci]; }
  for (int co = tid; co < 16; co += 256) {
    float a = c1b[co];
    for (int k = 0; k < 3; k++) for (int ci = 0; ci < 10; ci++) a += t1[ci] * c1w[(k * 10 + ci) * 16 + co];
    b1f[co] = a;
  }
  for (int i = tid; i < 3072; i += 256) { int ci = (i >> 5) & 15; w2f[i] = c2w[i] * s2[ci]; }
  for (int co = tid; co < 32; co += 256) {
    float a = c2b[co];
    for (int k = 0; k < 6; k++) for (int ci = 0; ci < 16; ci++) a += t2[ci] * c2w[(k * 16 + ci) * 32 + co];
    b2f[co] = a;
  }
  // biases
  for (int j = tid; j < 128; j += 256) {
    float a = l1b[j];
    for (int k = 0; k < 32; k++) a += t3[k] * l1W[k * 128 + j];
    bL1[j] = a;
  }
  for (int j = tid; j < 96; j += 256) bL2[j] = l2b[j];
  for (int j = tid; j < 64; j += 256) bL3[j] = l3b[j];

  // B-frag packs: lane l holds col n = nt*16+(l&15), k = kt*32+(l>>4)*8+e (e=0..7)
  // L1: W1[64][128], k<32: x-part (BN3 scale), k>=32: U
  for (int i = tid; i < 2 * 8 * 64 * 8; i += 256) {
    int e = i & 7, l = (i >> 3) & 63, nt = (i >> 9) & 7, kt = i >> 12;
    int j = nt * 16 + (l & 15);
    int k = kt * 32 + ((l >> 4) << 3) + e;
    float v = (k < 32) ? l1W[k * 128 + j] * s3[k] : l1U[(k - 32) * 128 + j];
    B1P[i] = f2b(v);
  }
  // L2: W2[64][96], k<32: h1-part (W), 32<=k<56: U, pad 0
  for (int i = tid; i < 2 * 6 * 64 * 8; i += 256) {
    int e = i & 7, l = (i >> 3) & 63, m = i >> 9;
    int nt = m % 6, kt = m / 6;
    int j = nt * 16 + (l & 15);
    int k = kt * 32 + ((l >> 4) << 3) + e;
    float v = (k < 32) ? l2W[k * 96 + j] : ((k < 56) ? l2U[(k - 32) * 96 + j] : 0.f);
    B2P[i] = f2b(v);
  }
  // L3: W3[64][64], k<24: W, 24<=k<40: U, pad 0
  for (int i = tid; i < 2 * 4 * 64 * 8; i += 256) {
    int e = i & 7, l = (i >> 3) & 63, m = i >> 9;
    int nt = m & 3, kt = m >> 2;
    int j = nt * 16 + (l & 15);
    int k = kt * 32 + ((l >> 4) << 3) + e;
    float v = (k < 24) ? l3W[k * 64 + j] : ((k < 40) ? l3U[(k - 24) * 64 + j] : 0.f);
    B3P[i] = f2b(v);
  }
}

// ---------------- fused conv1+ReLU+conv2+ReLU, bf16 output ----------------
#define CT 128
__global__ __launch_bounds__(256, 4) void conv_kernel(
    const float* __restrict__ x, const float* __restrict__ ws,
    unsigned short* __restrict__ r2, int row0)
{
  int b  = row0 + blockIdx.y;
  int bl = blockIdx.y;
  int t0 = blockIdx.x * CT;
  int n2 = min(CT, 505 - t0);
  int n1 = n2 + 5;
  int nx = n1 + 2;
  int tid = threadIdx.x;

  __shared__ float xs[135 * 10];
  __shared__ float r1s[133 * 17];
  __shared__ float w1f[480];
  __shared__ float b1f[16];
  alignas(16) __shared__ float w2f[3072];
  __shared__ float b2f[32];

  for (int i = tid; i < 480;  i += 256) w1f[i] = ws[WS_W1F + i];
  for (int i = tid; i < 16;   i += 256) b1f[i] = ws[WS_B1F + i];
  for (int i = tid; i < 32;   i += 256) b2f[i] = ws[WS_B2F + i];
  for (int i = tid; i < 3072; i += 256) w2f[i] = ws[WS_W2F + i];
  const float* xb = x + (size_t)b * 512 * 10 + (size_t)t0 * 10;
  for (int i = tid; i < nx * 10; i += 256) xs[i] = xb[i];
  __syncthreads();

  #pragma unroll 1
  for (int i = tid; i < n1 * 16; i += 256) {
    int tt = i >> 4, c = i & 15;
    float a = b1f[c];
    #pragma unroll
    for (int k = 0; k < 3; k++)
      #pragma unroll
      for (int ci = 0; ci < 10; ci++)
        a = fmaf(xs[(tt + k) * 10 + ci], w1f[(k * 10 + ci) * 16 + c], a);
    r1s[tt * 17 + c] = fmaxf(a, 0.f);
  }
  __syncthreads();

  int cog = (tid & 7) * 4;
  int tg  = (tid >> 3) * 4;
  float acc[4][4];
  #pragma unroll
  for (int i2 = 0; i2 < 4; i2++)
    #pragma unroll
    for (int j2 = 0; j2 < 4; j2++) acc[i2][j2] = b2f[cog + j2];
  #pragma unroll 4
  for (int kc = 0; kc < 96; kc++) {
    int k2 = kc >> 4;
    float4 w4 = *(const float4*)&w2f[kc * 32 + cog];
    #pragma unroll
    for (int i2 = 0; i2 < 4; i2++) {
      float xv = r1s[(tg + i2 + k2) * 17 + (kc & 15)];
      acc[i2][0] = fmaf(xv, w4.x, acc[i2][0]);
      acc[i2][1] = fmaf(xv, w4.y, acc[i2][1]);
      acc[i2][2] = fmaf(xv, w4.z, acc[i2][2]);
      acc[i2][3] = fmaf(xv, w4.w, acc[i2][3]);
    }
  }
  #pragma unroll
  for (int i2 = 0; i2 < 4; i2++) {
    int tt = tg + i2;
    if (tt < n2) {
      ull o = (ull)f2b(fmaxf(acc[i2][0], 0.f))
            | ((ull)f2b(fmaxf(acc[i2][1], 0.f)) << 16)
            | ((ull)f2b(fmaxf(acc[i2][2], 0.f)) << 32)
            | ((ull)f2b(fmaxf(acc[i2][3], 0.f)) << 48);
      *(ull*)&r2[((size_t)bl * 505 + (t0 + tt)) * 32 + cog] = o;
    }
  }
}

// ---------------- MFMA LSTM chain: 16 rows/block, 256 threads ----------------
#define SWZB(row, byte) ((byte) ^ (((row) & 7) << 4))
#define ZST 132

#define MFMA(a, b, c) __builtin_amdgcn_mfma_f32_16x16x32_bf16((a), (b), (c), 0, 0, 0)

__global__ __launch_bounds__(256) void lstm_kernel(
    const unsigned short* __restrict__ r2, const float* __restrict__ ws,
    const float* __restrict__ d1w, const float* __restrict__ d1b,
    const float* __restrict__ outw, const float* __restrict__ outb,
    float* __restrict__ out, int row0)
{
  int tid = threadIdx.x;
  int l   = tid & 63;
  int w   = tid >> 6;          // wave 0..3
  int r16 = l & 15;            // frag row / col-in-tile
  int g   = l >> 4;            // k-subgroup 0..3
  int rl  = blockIdx.x * 16;   // local row base

  alignas(16) __shared__ unsigned short xh1[16 * 64];  // [row][k]: k0..31=x_t, 32..63=h1
  alignas(16) __shared__ unsigned short xh2[16 * 64];  // k0..31=h1_t, 32..55=h2, pad
  alignas(16) __shared__ unsigned short xh3[16 * 64];  // k0..23=h2_t, 24..39=h3, pad
  __shared__ float zbf[16 * ZST];

  const unsigned short* B1P = (const unsigned short*)(ws + WS_B1P);
  const unsigned short* B2P = (const unsigned short*)(ws + WS_B2P);
  const unsigned short* B3P = (const unsigned short*)(ws + WS_B3P);

  // ---- B-fragment preload (held in VGPRs across all 505 steps)
  int nt1a = 2 * w, nt1b = 2 * w + 1;
  bool has2 = (w < 2);
  int nt2a = has2 ? 2 * w : (2 + w);       // 0,2,4,5
  int nt2b = has2 ? 2 * w + 1 : nt2a;      // 1,3,(dup)
  bf16x8 B1r[2][2], B2r[2][2], B3r[2];
  #pragma unroll
  for (int kt = 0; kt < 2; kt++) {
    B1r[kt][0] = *(const bf16x8*)&B1P[((kt * 8 + nt1a) * 64 + l) * 8];
    B1r[kt][1] = *(const bf16x8*)&B1P[((kt * 8 + nt1b) * 64 + l) * 8];
    B2r[kt][0] = *(const bf16x8*)&B2P[((kt * 6 + nt2a) * 64 + l) * 8];
    B2r[kt][1] = *(const bf16x8*)&B2P[((kt * 6 + nt2b) * 64 + l) * 8];
    B3r[kt]    = *(const bf16x8*)&B3P[((kt * 4 + w) * 64 + l) * 8];
  }
  float b1a = ws[WS_BL1 + nt1a * 16 + r16];
  float b1b = ws[WS_BL1 + nt1b * 16 + r16];
  float b2a = ws[WS_BL2 + nt2a * 16 + r16];
  float b2b = ws[WS_BL2 + nt2b * 16 + r16];
  float b3  = ws[WS_BL3 + w * 16 + r16];

  // ---- per-thread gate-set mappings (step-invariant) + cell regs
  int u1 = tid & 31, r1a = tid >> 5;           // L1: sets (r1a,u1),(r1a+8,u1)
  int s2a = tid, r2a = s2a / 24, u2a = s2a - r2a * 24;        // L2 set A
  int s2b = tid + 256, r2b = s2b / 24, u2b = s2b - r2b * 24;  // L2 set B (tid<128)
  int u3 = tid & 15, r3a = tid >> 4;           // L3
  float c1A = 0.f, c1B = 0.f, c2A = 0.f, c2B = 0.f, c3 = 0.f;

  // ---- init LDS (zeros incl. pads), stage x_0, prefetch x_1
  for (int i = tid; i < 16 * 64; i += 256) { xh1[i] = 0; xh2[i] = 0; xh3[i] = 0; }
  int xrow = tid >> 3, xch = tid & 7;
  const unsigned short* xp = r2 + ((size_t)(rl + xrow) * 505) * 32 + xch * 4;
  ull xreg = 0;
  if (tid < 128) xreg = *(const ull*)xp;
  __syncthreads();
  if (tid < 128) {
    *(ull*)((char*)xh1 + SWZB(xrow, xrow * 128 + xch * 8)) = xreg;
    xreg = *(const ull*)(xp + 32);
  }
  __syncthreads();

  #pragma unroll 1
  for (int t = 0; t < 505; ++t) {
    // ---------- Z1: [16x64] @ [64x128]
    {
      bf16x8 a0 = *(const bf16x8*)((const char*)xh1 + SWZB(r16, r16 * 128 + g * 16));
      bf16x8 a1 = *(const bf16x8*)((const char*)xh1 + SWZB(r16, r16 * 128 + 64 + g * 16));
      f32x4 acc0 = {b1a, b1a, b1a, b1a};
      f32x4 acc1 = {b1b, b1b, b1b, b1b};
      acc0 = MFMA(a0, B1r[0][0], acc0);
      acc1 = MFMA(a0, B1r[0][1], acc1);
      acc0 = MFMA(a1, B1r[1][0], acc0);
      acc1 = MFMA(a1, B1r[1][1], acc1);
      int c0 = nt1a * 16 + r16, c1c = nt1b * 16 + r16;
      #pragma unroll
      for (int q = 0; q < 4; q++) {
        zbf[(g * 4 + q) * ZST + c0]  = acc0[q];
        zbf[(g * 4 + q) * ZST + c1c] = acc1[q];
      }
    }
    __syncthreads();  // B1
    // ---------- U1: commit x_{t+1}, prefetch x_{t+2}, L1 gates
    if (tid < 128) {
      if (t < 504) *(ull*)((char*)xh1 + SWZB(xrow, xrow * 128 + xch * 8)) = xreg;
      if (t < 503) xreg = *(const ull*)(xp + (size_t)(t + 2) * 32);
    }
    {
      const float* z = &zbf[r1a * ZST];
      float gi = sigm(z[u1]), gf = sigm(z[32 + u1]), gg = tanh_(z[64 + u1]), go = sigm(z[96 + u1]);
      c1A = fmaf(gf, c1A, gi * gg);
      unsigned short hb = f2b(go * tanh_(c1A));
      *(unsigned short*)((char*)xh1 + SWZB(r1a, r1a * 128 + (32 + u1) * 2)) = hb;
      *(unsigned short*)((char*)xh2 + SWZB(r1a, r1a * 128 + u1 * 2)) = hb;
      int rB = r1a + 8;
      const float* zB = &zbf[rB * ZST];
      gi = sigm(zB[u1]); gf = sigm(zB[32 + u1]); gg = tanh_(zB[64 + u1]); go = sigm(zB[96 + u1]);
      c1B = fmaf(gf, c1B, gi * gg);
      hb = f2b(go * tanh_(c1B));
      *(unsigned short*)((char*)xh1 + SWZB(rB, rB * 128 + (32 + u1) * 2)) = hb;
      *(unsigned short*)((char*)xh2 + SWZB(rB, rB * 128 + u1 * 2)) = hb;
    }
    __syncthreads();  // B2
    // ---------- Z2: [16x64] @ [64x96]
    {
      bf16x8 a0 = *(const bf16x8*)((const char*)xh2 + SWZB(r16, r16 * 128 + g * 16));
      bf16x8 a1 = *(const bf16x8*)((const char*)xh2 + SWZB(r16, r16 * 128 + 64 + g * 16));
      f32x4 acc0 = {b2a, b2a, b2a, b2a};
      acc0 = MFMA(a0, B2r[0][0], acc0);
      acc0 = MFMA(a1, B2r[1][0], acc0);
      int c0 = nt2a * 16 + r16;
      if (has2) {
        f32x4 acc1 = {b2b, b2b, b2b, b2b};
        acc1 = MFMA(a0, B2r[0][1], acc1);
        acc1 = MFMA(a1, B2r[1][1], acc1);
        int c1c = nt2b * 16 + r16;
        #pragma unroll
        for (int q = 0; q < 4; q++) {
          zbf[(g * 4 + q) * ZST + c0]  = acc0[q];
          zbf[(g * 4 + q) * ZST + c1c] = acc1[q];
        }
      } else {
        #pragma unroll
        for (int q = 0; q < 4; q++) zbf[(g * 4 + q) * ZST + c0] = acc0[q];
      }
    }
    __syncthreads();  // B3
    // ---------- U2: L2 gates (H=24): 384 sets
    {
      const float* z = &zbf[r2a * ZST];
      float gi = sigm(z[u2a]), gf = sigm(z[24 + u2a]), gg = tanh_(z[48 + u2a]), go = sigm(z[72 + u2a]);
      c2A = fmaf(gf, c2A, gi * gg);
      unsigned short hb = f2b(go * tanh_(c2A));
      *(unsigned short*)((char*)xh2 + SWZB(r2a, r2a * 128 + (32 + u2a) * 2)) = hb;
      *(unsigned short*)((char*)xh3 + SWZB(r2a, r2a * 128 + u2a * 2)) = hb;
      if (tid < 128) {
        const float* zB = &zbf[r2b * ZST];
        gi = sigm(zB[u2b]); gf = sigm(zB[24 + u2b]); gg = tanh_(zB[48 + u2b]); go = sigm(zB[72 + u2b]);
        c2B = fmaf(gf, c2B, gi * gg);
        hb = f2b(go * tanh_(c2B));
        *(unsigned short*)((char*)xh2 + SWZB(r2b, r2b * 128 + (32 + u2b) * 2)) = hb;
        *(unsigned short*)((char*)xh3 + SWZB(r2b, r2b * 128 + u2b * 2)) = hb;
      }
    }
    __syncthreads();  // B4
    // ---------- Z3: [16x64] @ [64x64]
    {
      bf16x8 a0 = *(const bf16x8*)((const char*)xh3 + SWZB(r16, r16 * 128 + g * 16));
      bf16x8 a1 = *(const bf16x8*)((const char*)xh3 + SWZB(r16, r16 * 128 + 64 + g * 16));
      f32x4 acc0 = {b3, b3, b3, b3};
      acc0 = MFMA(a0, B3r[0], acc0);
      acc0 = MFMA(a1, B3r[1], acc0);
      int c0 = w * 16 + r16;
      #pragma unroll
      for (int q = 0; q < 4; q++) zbf[(g * 4 + q) * ZST + c0] = acc0[q];
    }
    __syncthreads();  // B5
    // ---------- U3: L3 gates (H=16): 256 sets; stash h3 (f32) for head
    {
      const float* z = &zbf[r3a * ZST];
      float gi = sigm(z[u3]), gf = sigm(z[16 + u3]), gg = tanh_(z[32 + u3]), go = sigm(z[48 + u3]);
      c3 = fmaf(gf, c3, gi * gg);
      float h = go * tanh_(c3);
      *(unsigned short*)((char*)xh3 + SWZB(r3a, r3a * 128 + (24 + u3) * 2)) = f2b(h);
      zbf[r3a * ZST + 64 + u3] = h;   // f32 stash, read after final step
    }
    __syncthreads();  // B6
  }

  // ---------- dense head: 16 rows, 1 thread each
  if (tid < 16) {
    int row = tid;
    float hd[16];
    #pragma unroll
    for (int u = 0; u < 16; u++) hd[u] = zbf[row * ZST + 64 + u];
    float aa[8];
    #pragma unroll
    for (int o = 0; o < 8; o++) {
      float acc = d1b[o];
      #pragma unroll
      for (int u = 0; u < 16; u++) acc = fmaf(hd[u], d1w[u * 8 + o], acc);
      aa[o] = fmaxf(acc, 0.f);
    }
    float oo[5]; float mx = -1e30f;
    #pragma unroll
    for (int cc = 0; cc < 5; cc++) {
      float acc = outb[cc];
      #pragma unroll
      for (int o = 0; o < 8; o++) acc = fmaf(aa[o], outw[o * 5 + cc], acc);
      oo[cc] = acc; mx = fmaxf(mx, acc);
    }
    float sum = 0.f;
    #pragma unroll
    for (int cc = 0; cc < 5; cc++) { oo[cc] = __expf(oo[cc] - mx); sum += oo[cc]; }
    float inv = 1.f / sum;
    #pragma unroll
    for (int cc = 0; cc < 5; cc++) out[(size_t)(row0 + rl + row) * 5 + cc] = oo[cc] * inv;
  }
}

// ---------------- launch ----------------
extern "C" void kernel_launch(void* const* d_in, const int* in_sizes, int n_in,
                              void* d_out, int out_size, void* d_ws, size_t ws_size,
                              hipStream_t stream)
{
  const float* x    = (const float*)d_in[0];
  const float* bn1g = (const float*)d_in[1];
  const float* bn1b = (const float*)d_in[2];
  const float* bn1m = (const float*)d_in[3];
  const float* bn1v = (const float*)d_in[4];
  const float* bn2g = (const float*)d_in[5];
  const float* bn2b = (const float*)d_in[6];
  const float* bn2m = (const float*)d_in[7];
  const float* bn2v = (const float*)d_in[8];
  const float* bn3g = (const float*)d_in[9];
  const float* bn3b = (const float*)d_in[10];
  const float* bn3m = (const float*)d_in[11];
  const float* bn3v = (const float*)d_in[12];
  const float* c1w  = (const float*)d_in[13];
  const float* c1b  = (const float*)d_in[14];
  const float* c2w  = (const float*)d_in[15];
  const float* c2b  = (const float*)d_in[16];
  const float* l1W  = (const float*)d_in[17];
  const float* l1U  = (const float*)d_in[18];
  const float* l1b  = (const float*)d_in[19];
  const float* l2W  = (const float*)d_in[20];
  const float* l2U  = (const float*)d_in[21];
  const float* l2b  = (const float*)d_in[22];
  const float* l3W  = (const float*)d_in[23];
  const float* l3U  = (const float*)d_in[24];
  const float* l3b  = (const float*)d_in[25];
  const float* d1w  = (const float*)d_in[26];
  const float* d1b  = (const float*)d_in[27];
  const float* outw = (const float*)d_in[28];
  const float* outb = (const float*)d_in[29];

  float* ws = (float*)d_ws;
  unsigned short* r2 = (unsigned short*)(ws + WS_R2);

  prep_kernel<<<1, 256, 0, stream>>>(bn1g, bn1b, bn1m, bn1v,
                                     bn2g, bn2b, bn2m, bn2v,
                                     bn3g, bn3b, bn3m, bn3v,
                                     c1w, c1b, c2w, c2b,
                                     l1W, l1U, l1b, l2W, l2U, l2b, l3W, l3U, l3b,
                                     ws);

  // chunk if workspace too small for full bf16 r2 (132 MB)
  size_t availB = (ws_size > (size_t)WS_R2 * 4) ? ws_size - (size_t)WS_R2 * 4 : 0;
  int nch = 1;
  while ((size_t)(4096 / nch) * 505 * 32 * 2 > availB && nch < 16) nch <<= 1;
  int rows_pc = 4096 / nch;

  for (int ch = 0; ch < nch; ++ch) {
    int row0 = ch * rows_pc;
    dim3 cgrid(4, rows_pc);
    conv_kernel<<<cgrid, 256, 0, stream>>>(x, ws, r2, row0);
    lstm_kernel<<<rows_pc / 16, 256, 0, stream>>>(r2, ws, d1w, d1b, outw, outb, (float*)d_out, row0);
  }
}

// Round 4
// 1087.849 us; speedup vs baseline: 9.8054x; 1.2050x over previous
//
#include <hip/hip_runtime.h>
#include <math.h>

#define EPSBN 1e-3f

typedef unsigned long long ull;
typedef __attribute__((ext_vector_type(8))) short bf16x8;
typedef __attribute__((ext_vector_type(4))) float f32x4;

// ---------------- workspace layout (float offsets) ----------------
#define WS_W1F 0        // 480   conv1 w (BN1 folded)
#define WS_B1F 480      // 16
#define WS_B2F 496      // 32
#define WS_W2F 528      // 3072  conv2 w (BN2 folded) -> 3600
#define WS_BL1 3600     // 128   lstm1 bias (BN3 folded)
#define WS_BL2 3728     // 96
#define WS_BL3 3824     // 64 -> 3888
#define WS_B1P 3888     // 8192 ushort (bf16 B-frags L1) = 4096 f -> 7984
#define WS_B2P 7984     // 6144 ushort = 3072 f -> 11056
#define WS_B3P 11056    // 4096 ushort = 2048 f -> 13104
#define WS_R2  13104    // r2 in bf16 (ushort), rows*505*32

__device__ __forceinline__ unsigned short f2b(float f) {
  unsigned u = __float_as_uint(f);
  return (unsigned short)((u + 0x7FFFu + ((u >> 16) & 1u)) >> 16);  // RNE
}
__device__ __forceinline__ float sigm(float v) { return 1.f / (1.f + __expf(-v)); }
__device__ __forceinline__ float tanh_(float v) {
  float e = __expf(-2.f * fabsf(v));
  float t = (1.f - e) / (1.f + e);
  return copysignf(t, v);
}
// one LSTM gate-set: z -> (updated c, h)
__device__ __forceinline__ float gate_h(const float* __restrict__ z, int H, int u, float& c) {
  float gi = sigm(z[u]), gf = sigm(z[H + u]), gg = tanh_(z[2 * H + u]), go = sigm(z[3 * H + u]);
  c = fmaf(gf, c, gi * gg);
  return go * tanh_(c);
}

// ---------------- prep: fold BN, pack MFMA B-fragments (bf16) ----------------
__global__ __launch_bounds__(256) void prep_kernel(
    const float* __restrict__ bn1g, const float* __restrict__ bn1b,
    const float* __restrict__ bn1m, const float* __restrict__ bn1v,
    const float* __restrict__ bn2g, const float* __restrict__ bn2b,
    const float* __restrict__ bn2m, const float* __restrict__ bn2v,
    const float* __restrict__ bn3g, const float* __restrict__ bn3b,
    const float* __restrict__ bn3m, const float* __restrict__ bn3v,
    const float* __restrict__ c1w, const float* __restrict__ c1b,
    const float* __restrict__ c2w, const float* __restrict__ c2b,
    const float* __restrict__ l1W, const float* __restrict__ l1U, const float* __restrict__ l1b,
    const float* __restrict__ l2W, const float* __restrict__ l2U, const float* __restrict__ l2b,
    const float* __restrict__ l3W, const float* __restrict__ l3U, const float* __restrict__ l3b,
    float* __restrict__ ws)
{
  __shared__ float s1[10], t1[10], s2[16], t2[16], s3[32], t3[32];
  int tid = threadIdx.x;
  if (tid < 10)                  { float s = bn1g[tid] * rsqrtf(bn1v[tid] + EPSBN); s1[tid] = s; t1[tid] = bn1b[tid] - bn1m[tid] * s; }
  else if (tid >= 32 && tid < 48){ int c = tid - 32; float s = bn2g[c] * rsqrtf(bn2v[c] + EPSBN); s2[c] = s; t2[c] = bn2b[c] - bn2m[c] * s; }
  else if (tid >= 64 && tid < 96){ int c = tid - 64; float s = bn3g[c] * rsqrtf(bn3v[c] + EPSBN); s3[c] = s; t3[c] = bn3b[c] - bn3m[c] * s; }
  __syncthreads();

  float* w1f = ws + WS_W1F;
  float* b1f = ws + WS_B1F;
  float* b2f = ws + WS_B2F;
  float* w2f = ws + WS_W2F;
  float* bL1 = ws + WS_BL1;
  float* bL2 = ws + WS_BL2;
  float* bL3 = ws + WS_BL3;
  unsigned short* B1P = (unsigned short*)(ws + WS_B1P);
  unsigned short* B2P = (unsigned short*)(ws + WS_B2P);
  unsigned short* B3P = (unsigned short*)(ws + WS_B3P);

  for (int i = tid; i < 480; i += 256) { int ci = (i >> 4) % 10; w1f[i] = c1w[i] * s1[ci]; }
  for (int co = tid; co < 16; co += 256) {
    float a = c1b[co];
    for (int k = 0; k < 3; k++) for (int ci = 0; ci < 10; ci++) a += t1[ci] * c1w[(k * 10 + ci) * 16 + co];
    b1f[co] = a;
  }
  for (int i = tid; i < 3072; i += 256) { int ci = (i >> 5) & 15; w2f[i] = c2w[i] * s2[ci]; }
  for (int co = tid; co < 32; co += 256) {
    float a = c2b[co];
    for (int k = 0; k < 6; k++) for (int ci = 0; ci < 16; ci++) a += t2[ci] * c2w[(k * 16 + ci) * 32 + co];
    b2f[co] = a;
  }
  for (int j = tid; j < 128; j += 256) {
    float a = l1b[j];
    for (int k = 0; k < 32; k++) a += t3[k] * l1W[k * 128 + j];
    bL1[j] = a;
  }
  for (int j = tid; j < 96; j += 256) bL2[j] = l2b[j];
  for (int j = tid; j < 64; j += 256) bL3[j] = l3b[j];

  // B-frag packs: lane l holds col n = nt*16+(l&15), k = kt*32+(l>>4)*8+e
  for (int i = tid; i < 2 * 8 * 64 * 8; i += 256) {
    int e = i & 7, l = (i >> 3) & 63, nt = (i >> 9) & 7, kt = i >> 12;
    int j = nt * 16 + (l & 15);
    int k = kt * 32 + ((l >> 4) << 3) + e;
    float v = (k < 32) ? l1W[k * 128 + j] * s3[k] : l1U[(k - 32) * 128 + j];
    B1P[i] = f2b(v);
  }
  for (int i = tid; i < 2 * 6 * 64 * 8; i += 256) {
    int e = i & 7, l = (i >> 3) & 63, m = i >> 9;
    int nt = m % 6, kt = m / 6;
    int j = nt * 16 + (l & 15);
    int k = kt * 32 + ((l >> 4) << 3) + e;
    float v = (k < 32) ? l2W[k * 96 + j] : ((k < 56) ? l2U[(k - 32) * 96 + j] : 0.f);
    B2P[i] = f2b(v);
  }
  for (int i = tid; i < 2 * 4 * 64 * 8; i += 256) {
    int e = i & 7, l = (i >> 3) & 63, m = i >> 9;
    int nt = m & 3, kt = m >> 2;
    int j = nt * 16 + (l & 15);
    int k = kt * 32 + ((l >> 4) << 3) + e;
    float v = (k < 24) ? l3W[k * 64 + j] : ((k < 40) ? l3U[(k - 24) * 64 + j] : 0.f);
    B3P[i] = f2b(v);
  }
}

// ---------------- fused conv1+ReLU+conv2+ReLU, bf16 output ----------------
#define CT 128
__global__ __launch_bounds__(256, 4) void conv_kernel(
    const float* __restrict__ x, const float* __restrict__ ws,
    unsigned short* __restrict__ r2, int row0)
{
  int b  = row0 + blockIdx.y;
  int bl = blockIdx.y;
  int t0 = blockIdx.x * CT;
  int n2 = min(CT, 505 - t0);
  int n1 = n2 + 5;
  int nx = n1 + 2;
  int tid = threadIdx.x;

  __shared__ float xs[135 * 10];
  __shared__ float r1s[133 * 17];
  __shared__ float w1f[480];
  __shared__ float b1f[16];
  alignas(16) __shared__ float w2f[3072];
  __shared__ float b2f[32];

  for (int i = tid; i < 480;  i += 256) w1f[i] = ws[WS_W1F + i];
  for (int i = tid; i < 16;   i += 256) b1f[i] = ws[WS_B1F + i];
  for (int i = tid; i < 32;   i += 256) b2f[i] = ws[WS_B2F + i];
  for (int i = tid; i < 3072; i += 256) w2f[i] = ws[WS_W2F + i];
  const float* xb = x + (size_t)b * 512 * 10 + (size_t)t0 * 10;
  for (int i = tid; i < nx * 10; i += 256) xs[i] = xb[i];
  __syncthreads();

  #pragma unroll 1
  for (int i = tid; i < n1 * 16; i += 256) {
    int tt = i >> 4, c = i & 15;
    float a = b1f[c];
    #pragma unroll
    for (int k = 0; k < 3; k++)
      #pragma unroll
      for (int ci = 0; ci < 10; ci++)
        a = fmaf(xs[(tt + k) * 10 + ci], w1f[(k * 10 + ci) * 16 + c], a);
    r1s[tt * 17 + c] = fmaxf(a, 0.f);
  }
  __syncthreads();

  int cog = (tid & 7) * 4;
  int tg  = (tid >> 3) * 4;
  float acc[4][4];
  #pragma unroll
  for (int i2 = 0; i2 < 4; i2++)
    #pragma unroll
    for (int j2 = 0; j2 < 4; j2++) acc[i2][j2] = b2f[cog + j2];
  #pragma unroll 4
  for (int kc = 0; kc < 96; kc++) {
    int k2 = kc >> 4;
    float4 w4 = *(const float4*)&w2f[kc * 32 + cog];
    #pragma unroll
    for (int i2 = 0; i2 < 4; i2++) {
      float xv = r1s[(tg + i2 + k2) * 17 + (kc & 15)];
      acc[i2][0] = fmaf(xv, w4.x, acc[i2][0]);
      acc[i2][1] = fmaf(xv, w4.y, acc[i2][1]);
      acc[i2][2] = fmaf(xv, w4.z, acc[i2][2]);
      acc[i2][3] = fmaf(xv, w4.w, acc[i2][3]);
    }
  }
  #pragma unroll
  for (int i2 = 0; i2 < 4; i2++) {
    int tt = tg + i2;
    if (tt < n2) {
      ull o = (ull)f2b(fmaxf(acc[i2][0], 0.f))
            | ((ull)f2b(fmaxf(acc[i2][1], 0.f)) << 16)
            | ((ull)f2b(fmaxf(acc[i2][2], 0.f)) << 32)
            | ((ull)f2b(fmaxf(acc[i2][3], 0.f)) << 48);
      *(ull*)&r2[((size_t)bl * 505 + (t0 + tt)) * 32 + cog] = o;
    }
  }
}

// ---------------- skewed-pipeline MFMA LSTM: 4 rows/block, 2 barriers/step ----------------
// iteration i: Z{L1@t=i, L2@t=i-1, L3@t=i-2} | barrier | U{same} | barrier
#define SWZB(row, byte) ((byte) ^ (((row) & 7) << 4))
#define MFMA(a, b, c) __builtin_amdgcn_mfma_f32_16x16x32_bf16((a), (b), (c), 0, 0, 0)
#define ZST1 132
#define ZST2 100
#define ZST3 68

__global__ __launch_bounds__(256, 4) void lstm_kernel(
    const unsigned short* __restrict__ r2, const float* __restrict__ ws,
    const float* __restrict__ d1w, const float* __restrict__ d1b,
    const float* __restrict__ outw, const float* __restrict__ outb,
    float* __restrict__ out, int row0)
{
  int tid = threadIdx.x;
  int l   = tid & 63;
  int w   = tid >> 6;          // wave 0..3
  int r16 = l & 15;
  int g   = l >> 4;
  int rl  = blockIdx.x * 4;    // 4 batch rows per block

  alignas(16) __shared__ unsigned short xh1[16 * 64];  // rows 0-3 live; 4-15 stay zero
  alignas(16) __shared__ unsigned short xh2[16 * 64];
  alignas(16) __shared__ unsigned short xh3[16 * 64];
  __shared__ float zb1[4 * ZST1];
  __shared__ float zb2[4 * ZST2];
  __shared__ float zb3[4 * ZST3];
  __shared__ float hstash[4 * 16];

  const unsigned short* B1P = (const unsigned short*)(ws + WS_B1P);
  const unsigned short* B2P = (const unsigned short*)(ws + WS_B2P);
  const unsigned short* B3P = (const unsigned short*)(ws + WS_B3P);

  // per-wave Z-phase parameters
  const unsigned short* Bp; const float* bbase; const unsigned short* xs8;
  float* zw; int zst, NJ, jo, ntt;
  if (w == 0)      { Bp = B1P; bbase = ws + WS_BL1; xs8 = xh1; zw = zb1; zst = ZST1; NJ = 4; jo = 0; ntt = 8; }
  else if (w == 1) { Bp = B1P; bbase = ws + WS_BL1; xs8 = xh1; zw = zb1; zst = ZST1; NJ = 4; jo = 4; ntt = 8; }
  else if (w == 2) { Bp = B2P; bbase = ws + WS_BL2; xs8 = xh2; zw = zb2; zst = ZST2; NJ = 6; jo = 0; ntt = 6; }
  else             { Bp = B3P; bbase = ws + WS_BL3; xs8 = xh3; zw = zb3; zst = ZST3; NJ = 4; jo = 0; ntt = 4; }

  bf16x8 Bfr[12];
  float barr[6];
  #pragma unroll
  for (int j = 0; j < 6; j++) {
    if (j < NJ) {
      Bfr[2 * j]     = *(const bf16x8*)&Bp[((0 * ntt + jo + j) * 64 + l) * 8];
      Bfr[2 * j + 1] = *(const bf16x8*)&Bp[((1 * ntt + jo + j) * 64 + l) * 8];
      barr[j] = bbase[(jo + j) * 16 + r16];
    } else {
      barr[j] = 0.f;
      Bfr[2 * j] = (bf16x8)0; Bfr[2 * j + 1] = (bf16x8)0;
    }
  }

  float cA = 0.f, cB = 0.f;   // cell regs: W0/W1:c1, W2:c2(A,B), W3:c3
  ull xreg = 0;
  const unsigned short* xp = nullptr;
  int xrow = 0, xch = 0;
  if (tid >= 224) {
    int slot = tid - 224;               // 0..31
    xrow = slot >> 3; xch = slot & 7;
    xp = r2 + ((size_t)(rl + xrow) * 505) * 32 + xch * 4;
    xreg = *(const ull*)xp;             // x(0)
  }

  for (int i = tid; i < 16 * 64; i += 256) { xh1[i] = 0; xh2[i] = 0; xh3[i] = 0; }
  if (tid < 64) hstash[tid] = 0.f;
  __syncthreads();
  if (tid >= 224) {
    *(ull*)((char*)xh1 + SWZB(xrow, xrow * 128 + xch * 8)) = xreg;  // commit x(0)
    xreg = *(const ull*)(xp + 32);                                  // x(1)
  }
  __syncthreads();

  #pragma unroll 1
  for (int i = 0; i < 507; ++i) {
    // ---------- Z phase: each wave its own layer's GEMM (A rows 4-15 are zeros)
    {
      bf16x8 a0 = *(const bf16x8*)((const char*)xs8 + SWZB(r16, r16 * 128 + g * 16));
      bf16x8 a1 = *(const bf16x8*)((const char*)xs8 + SWZB(r16, r16 * 128 + 64 + g * 16));
      #pragma unroll
      for (int j = 0; j < 6; j++) {
        if (j < NJ) {
          f32x4 ac = {barr[j], barr[j], barr[j], barr[j]};
          ac = MFMA(a0, Bfr[2 * j], ac);
          ac = MFMA(a1, Bfr[2 * j + 1], ac);
          if (g == 0) {                    // rows 0-3 live in lanes 0-15 (q=row)
            int c = (jo + j) * 16 + r16;
            #pragma unroll
            for (int q = 0; q < 4; q++) zw[q * zst + c] = ac[q];
          }
        }
      }
    }
    __syncthreads();  // A: z ready
    // ---------- U phase
    if (w < 2) {
      if (i <= 504) {                      // L1 step t=i
        int s = tid, r = s >> 5, u = s & 31;
        float h = gate_h(zb1 + r * ZST1, 32, u, cA);
        unsigned short hb = f2b(h);
        *(unsigned short*)((char*)xh1 + SWZB(r, r * 128 + (32 + u) * 2)) = hb;
        *(unsigned short*)((char*)xh2 + SWZB(r, r * 128 + u * 2)) = hb;
      }
    } else if (w == 2) {
      if (i >= 1 && i <= 505) {            // L2 step t=i-1
        int s = tid - 128;                 // set A: 0..63
        int r = s / 24, u = s - r * 24;
        float h = gate_h(zb2 + r * ZST2, 24, u, cA);
        unsigned short hb = f2b(h);
        *(unsigned short*)((char*)xh2 + SWZB(r, r * 128 + (32 + u) * 2)) = hb;
        *(unsigned short*)((char*)xh3 + SWZB(r, r * 128 + u * 2)) = hb;
        if (tid < 160) {                   // set B: 64..95
          int s2 = tid - 128 + 64;
          int rB = s2 / 24, uB = s2 - rB * 24;
          float hB = gate_h(zb2 + rB * ZST2, 24, uB, cB);
          unsigned short hbB = f2b(hB);
          *(unsigned short*)((char*)xh2 + SWZB(rB, rB * 128 + (32 + uB) * 2)) = hbB;
          *(unsigned short*)((char*)xh3 + SWZB(rB, rB * 128 + uB * 2)) = hbB;
        }
      }
    } else {
      if (i >= 2) {                        // L3 step t=i-2
        int s = tid - 192, r = s >> 4, u = s & 15;
        float h = gate_h(zb3 + r * ZST3, 16, u, cA);
        *(unsigned short*)((char*)xh3 + SWZB(r, r * 128 + (24 + u) * 2)) = f2b(h);
        hstash[r * 16 + u] = h;
      }
      if (tid >= 224) {                    // x staging (hidden under other waves' U)
        if (i < 504) *(ull*)((char*)xh1 + SWZB(xrow, xrow * 128 + xch * 8)) = xreg;
        if (i < 503) xreg = *(const ull*)(xp + (size_t)(i + 2) * 32);
      }
    }
    __syncthreads();  // B: h committed
  }

  // ---------- dense head: 4 rows, 1 thread each
  if (tid < 4) {
    int row = tid;
    float hd[16];
    #pragma unroll
    for (int u = 0; u < 16; u++) hd[u] = hstash[row * 16 + u];
    float aa[8];
    #pragma unroll
    for (int o = 0; o < 8; o++) {
      float acc = d1b[o];
      #pragma unroll
      for (int u = 0; u < 16; u++) acc = fmaf(hd[u], d1w[u * 8 + o], acc);
      aa[o] = fmaxf(acc, 0.f);
    }
    float oo[5]; float mx = -1e30f;
    #pragma unroll
    for (int cc = 0; cc < 5; cc++) {
      float acc = outb[cc];
      #pragma unroll
      for (int o = 0; o < 8; o++) acc = fmaf(aa[o], outw[o * 5 + cc], acc);
      oo[cc] = acc; mx = fmaxf(mx, acc);
    }
    float sum = 0.f;
    #pragma unroll
    for (int cc = 0; cc < 5; cc++) { oo[cc] = __expf(oo[cc] - mx); sum += oo[cc]; }
    float inv = 1.f / sum;
    #pragma unroll
    for (int cc = 0; cc < 5; cc++) out[(size_t)(row0 + rl + row) * 5 + cc] = oo[cc] * inv;
  }
}

// ---------------- launch ----------------
extern "C" void kernel_launch(void* const* d_in, const int* in_sizes, int n_in,
                              void* d_out, int out_size, void* d_ws, size_t ws_size,
                              hipStream_t stream)
{
  const float* x    = (const float*)d_in[0];
  const float* bn1g = (const float*)d_in[1];
  const float* bn1b = (const float*)d_in[2];
  const float* bn1m = (const float*)d_in[3];
  const float* bn1v = (const float*)d_in[4];
  const float* bn2g = (const float*)d_in[5];
  const float* bn2b = (const float*)d_in[6];
  const float* bn2m = (const float*)d_in[7];
  const float* bn2v = (const float*)d_in[8];
  const float* bn3g = (const float*)d_in[9];
  const float* bn3b = (const float*)d_in[10];
  const float* bn3m = (const float*)d_in[11];
  const float* bn3v = (const float*)d_in[12];
  const float* c1w  = (const float*)d_in[13];
  const float* c1b  = (const float*)d_in[14];
  const float* c2w  = (const float*)d_in[15];
  const float* c2b  = (const float*)d_in[16];
  const float* l1W  = (const float*)d_in[17];
  const float* l1U  = (const float*)d_in[18];
  const float* l1b  = (const float*)d_in[19];
  const float* l2W  = (const float*)d_in[20];
  const float* l2U  = (const float*)d_in[21];
  const float* l2b  = (const float*)d_in[22];
  const float* l3W  = (const float*)d_in[23];
  const float* l3U  = (const float*)d_in[24];
  const float* l3b  = (const float*)d_in[25];
  const float* d1w  = (const float*)d_in[26];
  const float* d1b  = (const float*)d_in[27];
  const float* outw = (const float*)d_in[28];
  const float* outb = (const float*)d_in[29];

  float* ws = (float*)d_ws;
  unsigned short* r2 = (unsigned short*)(ws + WS_R2);

  prep_kernel<<<1, 256, 0, stream>>>(bn1g, bn1b, bn1m, bn1v,
                                     bn2g, bn2b, bn2m, bn2v,
                                     bn3g, bn3b, bn3m, bn3v,
                                     c1w, c1b, c2w, c2b,
                                     l1W, l1U, l1b, l2W, l2U, l2b, l3W, l3U, l3b,
                                     ws);

  size_t availB = (ws_size > (size_t)WS_R2 * 4) ? ws_size - (size_t)WS_R2 * 4 : 0;
  int nch = 1;
  while ((size_t)(4096 / nch) * 505 * 32 * 2 > availB && nch < 16) nch <<= 1;
  int rows_pc = 4096 / nch;

  for (int ch = 0; ch < nch; ++ch) {
    int row0 = ch * rows_pc;
    dim3 cgrid(4, rows_pc);
    conv_kernel<<<cgrid, 256, 0, stream>>>(x, ws, r2, row0);
    lstm_kernel<<<rows_pc / 4, 256, 0, stream>>>(r2, ws, d1w, d1b, outw, outb, (float*)d_out, row0);
  }
}